// Round 12
// baseline (113.695 us; speedup 1.0000x reference)
//
#include <hip/hip_runtime.h>
#include <hip/hip_bf16.h>

// Shapes (fixed): B=4, T=64, L=128, D=768, H=12, d=64
#define NB 4
#define NT 64
#define NL 128
#define ND 768
#define NH 12
#define HD 64

typedef __attribute__((ext_vector_type(8))) short short8;
typedef __attribute__((ext_vector_type(4))) float f32x4;
typedef __attribute__((ext_vector_type(4))) unsigned int u32x4;

typedef __attribute__((address_space(3))) unsigned int lds_u32;
typedef __attribute__((address_space(1))) const unsigned int glob_u32;

static __device__ __forceinline__ unsigned short f2b(float x) {
    __hip_bfloat16 h = __float2bfloat16(x);   // RNE
    return *reinterpret_cast<unsigned short*>(&h);
}
static __device__ __forceinline__ float b2f(unsigned short u) {
    unsigned int v = ((unsigned int)u) << 16;
    union { unsigned int i; float f; } c; c.i = v; return c.f;
}
// async global->LDS, 16B/lane; LDS dest = base + lane*16 (wave-uniform base)
static __device__ __forceinline__ void gl2lds16(const void* g, void* l) {
    __builtin_amdgcn_global_load_lds((glob_u32*)g, (lds_u32*)l, 16, 0, 0);
}
// branchless RNE fp32->bf16 for two elems, packed into one u32 (no NaN in inputs)
static __device__ __forceinline__ unsigned rne2(unsigned lo, unsigned hi) {
    lo += 0x7FFFu + ((lo >> 16) & 1u);
    hi += 0x7FFFu + ((hi >> 16) & 1u);
    return __builtin_amdgcn_perm(hi, lo, 0x07060302u);  // [hi31:16 | lo31:16]
}

// conversion chunk boundaries (8-float chunks): te | Wq | edu | Wk | Wv
#define TE_C   3145728u
#define WQ_C   3219456u
#define EDU_C  3244032u
#define WK_C   3317760u
#define NCHUNK 3391488u   // == 3312 * 1024; TE_C == 3072 * 1024

// ---------------------------------------------------------------------------
// Kernel 1: streaming fp32 -> bf16, branchless bit-RNE (2.5 VALU ops/elem),
// nontemporal loads on the te path (te fp32 never re-read), ILP-4.
// ---------------------------------------------------------------------------
__global__ __launch_bounds__(256) void conv_bf16(
    const float* __restrict__ te, const float* __restrict__ Wq,
    const float* __restrict__ edu, const float* __restrict__ Wk,
    const float* __restrict__ Wv, unsigned short* __restrict__ dst)
{
    const unsigned base = blockIdx.x * 1024u + threadIdx.x;
    u32x4 a[4], b[4];
    if (blockIdx.x < 3072u) {
        #pragma unroll
        for (int i = 0; i < 4; i++) {
            const u32x4* s = (const u32x4*)(te + (size_t)(base + i * 256u) * 8u);
            a[i] = __builtin_nontemporal_load(s);
            b[i] = __builtin_nontemporal_load(s + 1);
        }
    } else {
        #pragma unroll
        for (int i = 0; i < 4; i++) {
            unsigned c = base + i * 256u;
            const float* s;
            if (c < WQ_C)       s = Wq  + (size_t)(c - TE_C)  * 8u;
            else if (c < EDU_C) s = edu + (size_t)(c - WQ_C)  * 8u;
            else if (c < WK_C)  s = Wk  + (size_t)(c - EDU_C) * 8u;
            else                s = Wv  + (size_t)(c - WK_C)  * 8u;
            a[i] = *(const u32x4*)s;
            b[i] = *(const u32x4*)(s + 4);
        }
    }
    #pragma unroll
    for (int i = 0; i < 4; i++) {
        u32x4 o;
        o.x = rne2(a[i].x, a[i].y);
        o.y = rne2(a[i].z, a[i].w);
        o.z = rne2(b[i].x, b[i].y);
        o.w = rne2(b[i].z, b[i].w);
        *(u32x4*)(dst + (size_t)(base + i * 256u) * 8u) = o;
    }
}

// ---------------------------------------------------------------------------
// Kernel 2: fused K/V projection (bf16 MFMA) + speaker-bucket prefix scan.
// (unchanged — verified rounds 4-10)
// ---------------------------------------------------------------------------
__global__ __launch_bounds__(256) void kvm(
    const unsigned short* __restrict__ edu_b,
    const unsigned short* __restrict__ wk_b,
    const unsigned short* __restrict__ wv_b,
    const int* __restrict__ spk,
    unsigned short* __restrict__ Mt)
{
    const int h = blockIdx.x, b = blockIdx.y, eh = blockIdx.z;

    __shared__ float bucket[8][32][65];
    __shared__ float k_s[64][68];
    __shared__ float v_s[64][36];
    __shared__ __align__(16) unsigned short stage[10240];
    __shared__ int spk_s[64];
    unsigned short* edu_s = stage;
    unsigned short* wk_s  = stage + 4096;
    unsigned short* wv_s  = stage + 8192;

    const int tid = threadIdx.x, lane = tid & 63, wvx = tid >> 6;
    const int lr = lane & 15, lg = lane >> 4, r8 = lane >> 3, l8 = lane & 7;

    { float* p = &bucket[0][0][0];
      for (int i = tid; i < 8 * 32 * 65; i += 256) p[i] = 0.f; }
    if (tid < 64) spk_s[tid] = spk[b * NT + tid];

    const unsigned short* edub = edu_b + (size_t)(b * 64) * ND;
    const unsigned short* wkb  = wk_b + (size_t)(h * 64) * ND;
    const unsigned short* wvb  = wv_b + (size_t)(h * 64 + eh * 32) * ND;

    f32x4 acc_k[4], acc_v[2];
    #pragma unroll
    for (int i = 0; i < 4; i++) acc_k[i] = (f32x4){0.f, 0.f, 0.f, 0.f};
    #pragma unroll
    for (int i = 0; i < 2; i++) acc_v[i] = (f32x4){0.f, 0.f, 0.f, 0.f};

    const int sswz = ((l8 ^ r8) * 8);

    for (int k0 = 0; k0 < ND; k0 += 64) {
        __syncthreads();
        #pragma unroll
        for (int j = 0; j < 5; j++) {
            const int cid = wvx * 5 + j;
            const unsigned short* gs; unsigned short* ls;
            if (cid < 8)       { gs = edub + (size_t)(cid * 8 + r8) * ND;        ls = edu_s + cid * 512; }
            else if (cid < 16) { gs = wkb  + (size_t)((cid - 8) * 8 + r8) * ND;  ls = wk_s + (cid - 8) * 512; }
            else               { gs = wvb  + (size_t)((cid - 16) * 8 + r8) * ND; ls = wv_s + (cid - 16) * 512; }
            gl2lds16(gs + k0 + sswz, ls);
        }
        __syncthreads();
        #pragma unroll
        for (int k32 = 0; k32 < 2; k32++) {
            const int cx = (((k32 * 4 + lg) ^ (lr & 7)) * 8);
            short8 eb = *(const short8*)&edu_s[(wvx * 16 + lr) * 64 + cx];
            #pragma unroll
            for (int jb = 0; jb < 4; jb++) {
                short8 ak = *(const short8*)&wk_s[(jb * 16 + lr) * 64 + cx];
                acc_k[jb] = __builtin_amdgcn_mfma_f32_16x16x32_bf16(ak, eb, acc_k[jb], 0, 0, 0);
            }
            #pragma unroll
            for (int jb = 0; jb < 2; jb++) {
                short8 av = *(const short8*)&wv_s[(jb * 16 + lr) * 64 + cx];
                acc_v[jb] = __builtin_amdgcn_mfma_f32_16x16x32_bf16(av, eb, acc_v[jb], 0, 0, 0);
            }
        }
    }

    {
        const int t = wvx * 16 + lr;
        #pragma unroll
        for (int jb = 0; jb < 4; jb++) *(f32x4*)&k_s[t][jb * 16 + lg * 4] = acc_k[jb];
        #pragma unroll
        for (int jb = 0; jb < 2; jb++) *(f32x4*)&v_s[t][jb * 16 + lg * 4] = acc_v[jb];
    }
    __syncthreads();

    const int e = tid & 31, dg = tid >> 5;
    for (int t = 0; t < NT; t++) {
        const int s = spk_s[t];
        const float vv = v_s[t][e];
        unsigned short tmp[8];
        #pragma unroll
        for (int jj = 0; jj < 8; jj++) {
            float m = bucket[s][e][dg * 8 + jj] + k_s[t][dg * 8 + jj] * vv;
            bucket[s][e][dg * 8 + jj] = m;
            tmp[jj] = f2b(m);
        }
        unsigned short* mpp = Mt + (((size_t)(b * NT + t) * NH + h) * HD + eh * 32 + e) * HD + dg * 8;
        *(short8*)mpp = *(short8*)tmp;
    }
}

// ---------------------------------------------------------------------------
// Kernel 3: fused bf16 MFMA  q^T = Wq_hp @ te^T (K=768), a = q @ M, residual.
// (round-9 exact — proven 59.5 us: counted-vmcnt ping-pong, Mt from global)
// ---------------------------------------------------------------------------
__global__ __launch_bounds__(256, 2) void fused_qm(
    const unsigned short* __restrict__ te_b,
    const unsigned short* __restrict__ wq_b,
    const unsigned short* __restrict__ Mt,
    float* __restrict__ out)
{
    const int orig = blockIdx.x;
    const int id   = (orig & 7) * 192 + (orig >> 3);   // bijective XCD swizzle
    const int hp   = id % 6;
    const int bt   = id / 6;

    __shared__ __align__(16) unsigned short smem[32768];   // 65536 B
    unsigned short* te0 = smem;              // [128][64] swizzled chunks
    unsigned short* te1 = smem + 8192;
    unsigned short* wq0 = smem + 16384;
    unsigned short* wq1 = smem + 24576;
    unsigned short* q_s = smem;              // phase 2: [128][136]

    const int tid  = threadIdx.x;
    const int lane = tid & 63;
    const int wvx  = tid >> 6;
    const int lr   = lane & 15;
    const int lg   = lane >> 4;
    const int wm   = wvx >> 1;
    const int wn   = wvx & 1;
    const int r8   = lane >> 3;
    const int l8   = lane & 7;
    const int sswz = (l8 ^ r8) * 8;          // pre-swizzled source chunk (ush)

    const unsigned short* teb = te_b + (size_t)bt * NL * ND;
    const unsigned short* wqb = wq_b + (size_t)hp * 128 * ND;

    f32x4 acc[4][4];
    #pragma unroll
    for (int i = 0; i < 4; i++)
        #pragma unroll
        for (int j = 0; j < 4; j++) acc[i][j] = (f32x4){0.f, 0.f, 0.f, 0.f};

    auto STAGE = [&](unsigned short* tebuf, unsigned short* wqbuf, int k0) {
        #pragma unroll
        for (int j = 0; j < 4; j++) {
            const int rbase = wvx * 32 + j * 8;     // wave-uniform dest base
            gl2lds16(teb + (size_t)(rbase + r8) * ND + k0 + sswz, tebuf + rbase * 64);
            gl2lds16(wqb + (size_t)(rbase + r8) * ND + k0 + sswz, wqbuf + rbase * 64);
        }
    };
    auto COMPUTE = [&](const unsigned short* tes, const unsigned short* wqs) {
        #pragma unroll
        for (int k32 = 0; k32 < 2; k32++) {
            const int cx = (((k32 * 4 + lg) ^ (lr & 7)) * 8);
            short8 af[4], bfv[4];
            #pragma unroll
            for (int tm = 0; tm < 4; tm++)
                af[tm] = *(const short8*)&wqs[(wm * 64 + tm * 16 + lr) * 64 + cx];
            #pragma unroll
            for (int tn = 0; tn < 4; tn++)
                bfv[tn] = *(const short8*)&tes[(wn * 64 + tn * 16 + lr) * 64 + cx];
            #pragma unroll
            for (int tm = 0; tm < 4; tm++)
                #pragma unroll
                for (int tn = 0; tn < 4; tn++)
                    acc[tm][tn] = __builtin_amdgcn_mfma_f32_16x16x32_bf16(
                        af[tm], bfv[tn], acc[tm][tn], 0, 0, 0);
        }
    };

    // ---- prologue: tile 0 into buf0, full drain once ----
    STAGE(te0, wq0, 0);
    asm volatile("s_waitcnt vmcnt(0)" ::: "memory");
    __builtin_amdgcn_sched_barrier(0);
    __builtin_amdgcn_s_barrier();

    // ---- K-loop: 12 tiles, 2 per iteration, counted vmcnt (never 0 mid-loop)
    #pragma unroll
    for (int kt = 0; kt < 12; kt += 2) {
        // even tile kt (buf0); prefetch tile kt+1 into buf1
        STAGE(te1, wq1, (kt + 1) * 64);
        asm volatile("s_waitcnt vmcnt(8)" ::: "memory");   // tile kt complete
        __builtin_amdgcn_sched_barrier(0);
        __builtin_amdgcn_s_barrier();
        COMPUTE(te0, wq0);
        asm volatile("s_waitcnt lgkmcnt(0)" ::: "memory"); // reads retired
        __builtin_amdgcn_s_barrier();                      // buf0 free for reuse
        // odd tile kt+1 (buf1); prefetch tile kt+2 into buf0
        if (kt + 2 < 12) {
            STAGE(te0, wq0, (kt + 2) * 64);
            asm volatile("s_waitcnt vmcnt(8)" ::: "memory");
        } else {
            asm volatile("s_waitcnt vmcnt(0)" ::: "memory");
        }
        __builtin_amdgcn_sched_barrier(0);
        __builtin_amdgcn_s_barrier();
        COMPUTE(te1, wq1);
        asm volatile("s_waitcnt lgkmcnt(0)" ::: "memory");
        __builtin_amdgcn_s_barrier();                      // buf1 free for reuse
    }

    // ---- q^T C-frags -> row-major bf16 q_s[l][d] (8B packed writes) ----
    #pragma unroll
    for (int tm = 0; tm < 4; tm++) {
        const int d0 = wm * 64 + tm * 16 + lg * 4;
        #pragma unroll
        for (int tn = 0; tn < 4; tn++) {
            const int ltok = wn * 64 + tn * 16 + lr;
            f32x4 a = acc[tm][tn];
            uint2 w2;
            w2.x = (unsigned)f2b(a.x) | ((unsigned)f2b(a.y) << 16);
            w2.y = (unsigned)f2b(a.z) | ((unsigned)f2b(a.w) << 16);
            *(uint2*)&q_s[ltok * 136 + d0] = w2;
        }
    }

    // ---- GEMM2 B-frags straight from global Mt (L2-hot); issue pre-barrier --
    const int h2 = wvx & 1;
    const int lh = wvx >> 1;
    const unsigned short* mp = Mt + ((size_t)(bt * NH) + hp * 2 + h2) * (HD * HD);
    short8 bfr[8];
    #pragma unroll
    for (int tn = 0; tn < 4; tn++)
        #pragma unroll
        for (int k32 = 0; k32 < 2; k32++)
            bfr[tn * 2 + k32] =
                *(const short8*)&mp[(tn * 16 + lr) * 64 + k32 * 32 + lg * 8];
    __syncthreads();            // q_s visible

    // ---- GEMM2: per-wave one (token-half, head), 64x64, K=64 ----
    f32x4 acc2[4][4];
    #pragma unroll
    for (int i = 0; i < 4; i++)
        #pragma unroll
        for (int j = 0; j < 4; j++) acc2[i][j] = (f32x4){0.f, 0.f, 0.f, 0.f};

    #pragma unroll
    for (int k32 = 0; k32 < 2; k32++) {
        const int ko = k32 * 32 + lg * 8;
        short8 af[4];
        #pragma unroll
        for (int tm = 0; tm < 4; tm++)
            af[tm] = *(const short8*)&q_s[(lh * 64 + tm * 16 + lr) * 136 + h2 * 64 + ko];
        #pragma unroll
        for (int tm = 0; tm < 4; tm++)
            #pragma unroll
            for (int tn = 0; tn < 4; tn++)
                acc2[tm][tn] = __builtin_amdgcn_mfma_f32_16x16x32_bf16(
                    af[tm], bfr[tn * 2 + k32], acc2[tm][tn], 0, 0, 0);
    }

    // ---- epilogue: out = bf16(te) + a (te_b L2-hot from staging) ----
    float* ob = out + (size_t)bt * NL * ND;
    #pragma unroll
    for (int tm = 0; tm < 4; tm++) {
        const int l0 = lh * 64 + tm * 16 + lg * 4;
        #pragma unroll
        for (int tn = 0; tn < 4; tn++) {
            const int cg = hp * 128 + h2 * 64 + tn * 16 + lr;
            f32x4 a = acc2[tm][tn];
            #pragma unroll
            for (int r = 0; r < 4; r++) {
                size_t gi = (size_t)(l0 + r) * ND + cg;
                ob[gi] = b2f(teb[gi]) + a[r];
            }
        }
    }
}

// ---------------------------------------------------------------------------
extern "C" void kernel_launch(void* const* d_in, const int* in_sizes, int n_in,
                              void* d_out, int out_size, void* d_ws, size_t ws_size,
                              hipStream_t stream)
{
    const int*   spk = (const int*)d_in[1];
    const float* te  = (const float*)d_in[2];
    const float* edu = (const float*)d_in[3];
    const float* Wk  = (const float*)d_in[4];
    const float* Wv  = (const float*)d_in[5];
    const float* Wq  = (const float*)d_in[6];
    float* out = (float*)d_out;

    // ws layout (ush units), ~79.4 MB total:
    unsigned short* bf    = (unsigned short*)d_ws;
    unsigned short* te_bb = bf;                          // 25165824
    unsigned short* wq_bb = bf + 25165824u;              //   589824
    unsigned short* edu_b = bf + 25755648u;              //   196608
    unsigned short* wk_bb = bf + 25952256u;              //   589824
    unsigned short* wv_bb = bf + 26542080u;              //   589824
    unsigned short* Mtbuf = bf + 27131904u;              // 12582912

    conv_bf16<<<3312,            256, 0, stream>>>(te, Wq, edu, Wk, Wv, bf);
    kvm      <<<dim3(NH, NB, 2), 256, 0, stream>>>(edu_b, wk_bb, wv_bb, spk, Mtbuf);
    fused_qm <<<6 * NT * NB,     256, 0, stream>>>(te_bb, wq_bb, Mtbuf, out);
}

// Round 13
// 112.393 us; speedup vs baseline: 1.0116x; 1.0116x over previous
//
#include <hip/hip_runtime.h>
#include <hip/hip_bf16.h>

// Shapes (fixed): B=4, T=64, L=128, D=768, H=12, d=64
#define NB 4
#define NT 64
#define NL 128
#define ND 768
#define NH 12
#define HD 64

typedef __attribute__((ext_vector_type(8))) short short8;
typedef __attribute__((ext_vector_type(4))) float f32x4;
typedef __attribute__((ext_vector_type(4))) unsigned int u32x4;

typedef __attribute__((address_space(3))) unsigned int lds_u32;
typedef __attribute__((address_space(1))) const unsigned int glob_u32;

static __device__ __forceinline__ unsigned short f2b(float x) {
    __hip_bfloat16 h = __float2bfloat16(x);   // RNE
    return *reinterpret_cast<unsigned short*>(&h);
}
static __device__ __forceinline__ float b2f(unsigned short u) {
    unsigned int v = ((unsigned int)u) << 16;
    union { unsigned int i; float f; } c; c.i = v; return c.f;
}
// async global->LDS, 16B/lane; LDS dest = base + lane*16 (wave-uniform base)
static __device__ __forceinline__ void gl2lds16(const void* g, void* l) {
    __builtin_amdgcn_global_load_lds((glob_u32*)g, (lds_u32*)l, 16, 0, 0);
}
// branchless RNE fp32->bf16 for two elems, packed into one u32 (no NaN in inputs)
static __device__ __forceinline__ unsigned rne2(unsigned lo, unsigned hi) {
    lo += 0x7FFFu + ((lo >> 16) & 1u);
    hi += 0x7FFFu + ((hi >> 16) & 1u);
    return __builtin_amdgcn_perm(hi, lo, 0x07060302u);  // [hi31:16 | lo31:16]
}

// ---------------------------------------------------------------------------
// Kernel 1: streaming fp32 -> bf16, DENSE addressing: each load instruction is
// 16 B/lane at 16 B lane stride (full-density; previous rounds used 32 B
// chunks/thread = half-density -> 3.2 TB/s). ILP-8 per thread.
// 4-float chunk boundaries (tail, relative): Wq|edu|Wk|Wv
// ---------------------------------------------------------------------------
#define TAIL_WQ4  147456u
#define TAIL_EDU4 196608u
#define TAIL_WK4  344064u
// te: 6291456 four-float chunks = 3072 blocks * 2048; tail: 491520 = 240 * 2048
__global__ __launch_bounds__(256) void conv_bf16(
    const float* __restrict__ te, const float* __restrict__ Wq,
    const float* __restrict__ edu, const float* __restrict__ Wk,
    const float* __restrict__ Wv, unsigned short* __restrict__ dst)
{
    const unsigned tid = threadIdx.x;
    if (blockIdx.x < 3072u) {
        const unsigned base = blockIdx.x * 2048u + tid;     // 4-float chunk id
        u32x4 a[8];
        #pragma unroll
        for (int i = 0; i < 8; i++) {
            const u32x4* s = (const u32x4*)te + (base + i * 256u);
            a[i] = __builtin_nontemporal_load(s);
        }
        #pragma unroll
        for (int i = 0; i < 8; i++) {
            uint2 o;
            o.x = rne2(a[i].x, a[i].y);
            o.y = rne2(a[i].z, a[i].w);
            *(uint2*)(dst + (size_t)(base + i * 256u) * 4u) = o;
        }
    } else {
        const unsigned base = (blockIdx.x - 3072u) * 2048u + tid;  // tail chunk id
        u32x4 a[8];
        #pragma unroll
        for (int i = 0; i < 8; i++) {
            unsigned c = base + i * 256u;
            const float* s;
            if (c < TAIL_WQ4)       s = Wq  + (size_t)c * 4u;
            else if (c < TAIL_EDU4) s = edu + (size_t)(c - TAIL_WQ4)  * 4u;
            else if (c < TAIL_WK4)  s = Wk  + (size_t)(c - TAIL_EDU4) * 4u;
            else                    s = Wv  + (size_t)(c - TAIL_WK4)  * 4u;
            a[i] = *(const u32x4*)s;
        }
        unsigned short* d = dst + 25165824u;   // tail dst starts after te_b
        #pragma unroll
        for (int i = 0; i < 8; i++) {
            uint2 o;
            o.x = rne2(a[i].x, a[i].y);
            o.y = rne2(a[i].z, a[i].w);
            *(uint2*)(d + (size_t)(base + i * 256u) * 4u) = o;
        }
    }
}

// ---------------------------------------------------------------------------
// Kernel 2: fused K/V projection (bf16 MFMA) + speaker-bucket prefix scan.
// (unchanged — verified rounds 4-12)
// ---------------------------------------------------------------------------
__global__ __launch_bounds__(256) void kvm(
    const unsigned short* __restrict__ edu_b,
    const unsigned short* __restrict__ wk_b,
    const unsigned short* __restrict__ wv_b,
    const int* __restrict__ spk,
    unsigned short* __restrict__ Mt)
{
    const int h = blockIdx.x, b = blockIdx.y, eh = blockIdx.z;

    __shared__ float bucket[8][32][65];
    __shared__ float k_s[64][68];
    __shared__ float v_s[64][36];
    __shared__ __align__(16) unsigned short stage[10240];
    __shared__ int spk_s[64];
    unsigned short* edu_s = stage;
    unsigned short* wk_s  = stage + 4096;
    unsigned short* wv_s  = stage + 8192;

    const int tid = threadIdx.x, lane = tid & 63, wvx = tid >> 6;
    const int lr = lane & 15, lg = lane >> 4, r8 = lane >> 3, l8 = lane & 7;

    { float* p = &bucket[0][0][0];
      for (int i = tid; i < 8 * 32 * 65; i += 256) p[i] = 0.f; }
    if (tid < 64) spk_s[tid] = spk[b * NT + tid];

    const unsigned short* edub = edu_b + (size_t)(b * 64) * ND;
    const unsigned short* wkb  = wk_b + (size_t)(h * 64) * ND;
    const unsigned short* wvb  = wv_b + (size_t)(h * 64 + eh * 32) * ND;

    f32x4 acc_k[4], acc_v[2];
    #pragma unroll
    for (int i = 0; i < 4; i++) acc_k[i] = (f32x4){0.f, 0.f, 0.f, 0.f};
    #pragma unroll
    for (int i = 0; i < 2; i++) acc_v[i] = (f32x4){0.f, 0.f, 0.f, 0.f};

    const int sswz = ((l8 ^ r8) * 8);

    for (int k0 = 0; k0 < ND; k0 += 64) {
        __syncthreads();
        #pragma unroll
        for (int j = 0; j < 5; j++) {
            const int cid = wvx * 5 + j;
            const unsigned short* gs; unsigned short* ls;
            if (cid < 8)       { gs = edub + (size_t)(cid * 8 + r8) * ND;        ls = edu_s + cid * 512; }
            else if (cid < 16) { gs = wkb  + (size_t)((cid - 8) * 8 + r8) * ND;  ls = wk_s + (cid - 8) * 512; }
            else               { gs = wvb  + (size_t)((cid - 16) * 8 + r8) * ND; ls = wv_s + (cid - 16) * 512; }
            gl2lds16(gs + k0 + sswz, ls);
        }
        __syncthreads();
        #pragma unroll
        for (int k32 = 0; k32 < 2; k32++) {
            const int cx = (((k32 * 4 + lg) ^ (lr & 7)) * 8);
            short8 eb = *(const short8*)&edu_s[(wvx * 16 + lr) * 64 + cx];
            #pragma unroll
            for (int jb = 0; jb < 4; jb++) {
                short8 ak = *(const short8*)&wk_s[(jb * 16 + lr) * 64 + cx];
                acc_k[jb] = __builtin_amdgcn_mfma_f32_16x16x32_bf16(ak, eb, acc_k[jb], 0, 0, 0);
            }
            #pragma unroll
            for (int jb = 0; jb < 2; jb++) {
                short8 av = *(const short8*)&wv_s[(jb * 16 + lr) * 64 + cx];
                acc_v[jb] = __builtin_amdgcn_mfma_f32_16x16x32_bf16(av, eb, acc_v[jb], 0, 0, 0);
            }
        }
    }

    {
        const int t = wvx * 16 + lr;
        #pragma unroll
        for (int jb = 0; jb < 4; jb++) *(f32x4*)&k_s[t][jb * 16 + lg * 4] = acc_k[jb];
        #pragma unroll
        for (int jb = 0; jb < 2; jb++) *(f32x4*)&v_s[t][jb * 16 + lg * 4] = acc_v[jb];
    }
    __syncthreads();

    const int e = tid & 31, dg = tid >> 5;
    for (int t = 0; t < NT; t++) {
        const int s = spk_s[t];
        const float vv = v_s[t][e];
        unsigned short tmp[8];
        #pragma unroll
        for (int jj = 0; jj < 8; jj++) {
            float m = bucket[s][e][dg * 8 + jj] + k_s[t][dg * 8 + jj] * vv;
            bucket[s][e][dg * 8 + jj] = m;
            tmp[jj] = f2b(m);
        }
        unsigned short* mpp = Mt + (((size_t)(b * NT + t) * NH + h) * HD + eh * 32 + e) * HD + dg * 8;
        *(short8*)mpp = *(short8*)tmp;
    }
}

// ---------------------------------------------------------------------------
// Kernel 3: fused bf16 MFMA  q^T = Wq_hp @ te^T (K=768), a = q @ M, residual.
// (round-9/12 exact — proven ~60 us: counted-vmcnt ping-pong, Mt from global)
// ---------------------------------------------------------------------------
__global__ __launch_bounds__(256, 2) void fused_qm(
    const unsigned short* __restrict__ te_b,
    const unsigned short* __restrict__ wq_b,
    const unsigned short* __restrict__ Mt,
    float* __restrict__ out)
{
    const int orig = blockIdx.x;
    const int id   = (orig & 7) * 192 + (orig >> 3);   // bijective XCD swizzle
    const int hp   = id % 6;
    const int bt   = id / 6;

    __shared__ __align__(16) unsigned short smem[32768];   // 65536 B
    unsigned short* te0 = smem;              // [128][64] swizzled chunks
    unsigned short* te1 = smem + 8192;
    unsigned short* wq0 = smem + 16384;
    unsigned short* wq1 = smem + 24576;
    unsigned short* q_s = smem;              // phase 2: [128][136]

    const int tid  = threadIdx.x;
    const int lane = tid & 63;
    const int wvx  = tid >> 6;
    const int lr   = lane & 15;
    const int lg   = lane >> 4;
    const int wm   = wvx >> 1;
    const int wn   = wvx & 1;
    const int r8   = lane >> 3;
    const int l8   = lane & 7;
    const int sswz = (l8 ^ r8) * 8;          // pre-swizzled source chunk (ush)

    const unsigned short* teb = te_b + (size_t)bt * NL * ND;
    const unsigned short* wqb = wq_b + (size_t)hp * 128 * ND;

    f32x4 acc[4][4];
    #pragma unroll
    for (int i = 0; i < 4; i++)
        #pragma unroll
        for (int j = 0; j < 4; j++) acc[i][j] = (f32x4){0.f, 0.f, 0.f, 0.f};

    auto STAGE = [&](unsigned short* tebuf, unsigned short* wqbuf, int k0) {
        #pragma unroll
        for (int j = 0; j < 4; j++) {
            const int rbase = wvx * 32 + j * 8;     // wave-uniform dest base
            gl2lds16(teb + (size_t)(rbase + r8) * ND + k0 + sswz, tebuf + rbase * 64);
            gl2lds16(wqb + (size_t)(rbase + r8) * ND + k0 + sswz, wqbuf + rbase * 64);
        }
    };
    auto COMPUTE = [&](const unsigned short* tes, const unsigned short* wqs) {
        #pragma unroll
        for (int k32 = 0; k32 < 2; k32++) {
            const int cx = (((k32 * 4 + lg) ^ (lr & 7)) * 8);
            short8 af[4], bfv[4];
            #pragma unroll
            for (int tm = 0; tm < 4; tm++)
                af[tm] = *(const short8*)&wqs[(wm * 64 + tm * 16 + lr) * 64 + cx];
            #pragma unroll
            for (int tn = 0; tn < 4; tn++)
                bfv[tn] = *(const short8*)&tes[(wn * 64 + tn * 16 + lr) * 64 + cx];
            #pragma unroll
            for (int tm = 0; tm < 4; tm++)
                #pragma unroll
                for (int tn = 0; tn < 4; tn++)
                    acc[tm][tn] = __builtin_amdgcn_mfma_f32_16x16x32_bf16(
                        af[tm], bfv[tn], acc[tm][tn], 0, 0, 0);
        }
    };

    // ---- prologue: tile 0 into buf0, full drain once ----
    STAGE(te0, wq0, 0);
    asm volatile("s_waitcnt vmcnt(0)" ::: "memory");
    __builtin_amdgcn_sched_barrier(0);
    __builtin_amdgcn_s_barrier();

    // ---- K-loop: 12 tiles, 2 per iteration, counted vmcnt (never 0 mid-loop)
    #pragma unroll
    for (int kt = 0; kt < 12; kt += 2) {
        // even tile kt (buf0); prefetch tile kt+1 into buf1
        STAGE(te1, wq1, (kt + 1) * 64);
        asm volatile("s_waitcnt vmcnt(8)" ::: "memory");   // tile kt complete
        __builtin_amdgcn_sched_barrier(0);
        __builtin_amdgcn_s_barrier();
        COMPUTE(te0, wq0);
        asm volatile("s_waitcnt lgkmcnt(0)" ::: "memory"); // reads retired
        __builtin_amdgcn_s_barrier();                      // buf0 free for reuse
        // odd tile kt+1 (buf1); prefetch tile kt+2 into buf0
        if (kt + 2 < 12) {
            STAGE(te0, wq0, (kt + 2) * 64);
            asm volatile("s_waitcnt vmcnt(8)" ::: "memory");
        } else {
            asm volatile("s_waitcnt vmcnt(0)" ::: "memory");
        }
        __builtin_amdgcn_sched_barrier(0);
        __builtin_amdgcn_s_barrier();
        COMPUTE(te1, wq1);
        asm volatile("s_waitcnt lgkmcnt(0)" ::: "memory");
        __builtin_amdgcn_s_barrier();                      // buf1 free for reuse
    }

    // ---- q^T C-frags -> row-major bf16 q_s[l][d] (8B packed writes) ----
    #pragma unroll
    for (int tm = 0; tm < 4; tm++) {
        const int d0 = wm * 64 + tm * 16 + lg * 4;
        #pragma unroll
        for (int tn = 0; tn < 4; tn++) {
            const int ltok = wn * 64 + tn * 16 + lr;
            f32x4 a = acc[tm][tn];
            uint2 w2;
            w2.x = (unsigned)f2b(a.x) | ((unsigned)f2b(a.y) << 16);
            w2.y = (unsigned)f2b(a.z) | ((unsigned)f2b(a.w) << 16);
            *(uint2*)&q_s[ltok * 136 + d0] = w2;
        }
    }

    // ---- GEMM2 B-frags straight from global Mt (L2-hot); issue pre-barrier --
    const int h2 = wvx & 1;
    const int lh = wvx >> 1;
    const unsigned short* mp = Mt + ((size_t)(bt * NH) + hp * 2 + h2) * (HD * HD);
    short8 bfr[8];
    #pragma unroll
    for (int tn = 0; tn < 4; tn++)
        #pragma unroll
        for (int k32 = 0; k32 < 2; k32++)
            bfr[tn * 2 + k32] =
                *(const short8*)&mp[(tn * 16 + lr) * 64 + k32 * 32 + lg * 8];
    __syncthreads();            // q_s visible

    // ---- GEMM2: per-wave one (token-half, head), 64x64, K=64 ----
    f32x4 acc2[4][4];
    #pragma unroll
    for (int i = 0; i < 4; i++)
        #pragma unroll
        for (int j = 0; j < 4; j++) acc2[i][j] = (f32x4){0.f, 0.f, 0.f, 0.f};

    #pragma unroll
    for (int k32 = 0; k32 < 2; k32++) {
        const int ko = k32 * 32 + lg * 8;
        short8 af[4];
        #pragma unroll
        for (int tm = 0; tm < 4; tm++)
            af[tm] = *(const short8*)&q_s[(lh * 64 + tm * 16 + lr) * 136 + h2 * 64 + ko];
        #pragma unroll
        for (int tm = 0; tm < 4; tm++)
            #pragma unroll
            for (int tn = 0; tn < 4; tn++)
                acc2[tm][tn] = __builtin_amdgcn_mfma_f32_16x16x32_bf16(
                    af[tm], bfr[tn * 2 + k32], acc2[tm][tn], 0, 0, 0);
    }

    // ---- epilogue: out = bf16(te) + a (te_b L2-hot from staging) ----
    float* ob = out + (size_t)bt * NL * ND;
    #pragma unroll
    for (int tm = 0; tm < 4; tm++) {
        const int l0 = lh * 64 + tm * 16 + lg * 4;
        #pragma unroll
        for (int tn = 0; tn < 4; tn++) {
            const int cg = hp * 128 + h2 * 64 + tn * 16 + lr;
            f32x4 a = acc2[tm][tn];
            #pragma unroll
            for (int r = 0; r < 4; r++) {
                size_t gi = (size_t)(l0 + r) * ND + cg;
                ob[gi] = b2f(teb[gi]) + a[r];
            }
        }
    }
}

// ---------------------------------------------------------------------------
extern "C" void kernel_launch(void* const* d_in, const int* in_sizes, int n_in,
                              void* d_out, int out_size, void* d_ws, size_t ws_size,
                              hipStream_t stream)
{
    const int*   spk = (const int*)d_in[1];
    const float* te  = (const float*)d_in[2];
    const float* edu = (const float*)d_in[3];
    const float* Wk  = (const float*)d_in[4];
    const float* Wv  = (const float*)d_in[5];
    const float* Wq  = (const float*)d_in[6];
    float* out = (float*)d_out;

    // ws layout (ush units), ~79.4 MB total:
    unsigned short* bf    = (unsigned short*)d_ws;
    unsigned short* te_bb = bf;                          // 25165824
    unsigned short* wq_bb = bf + 25165824u;              //   589824
    unsigned short* edu_b = bf + 25755648u;              //   196608
    unsigned short* wk_bb = bf + 25952256u;              //   589824
    unsigned short* wv_bb = bf + 26542080u;              //   589824
    unsigned short* Mtbuf = bf + 27131904u;              // 12582912

    conv_bf16<<<3312,            256, 0, stream>>>(te, Wq, edu, Wk, Wv, bf);
    kvm      <<<dim3(NH, NB, 2), 256, 0, stream>>>(edu_b, wk_bb, wv_bb, spk, Mtbuf);
    fused_qm <<<6 * NT * NB,     256, 0, stream>>>(te_bb, wq_bb, Mtbuf, out);
}

// Round 14
// 101.766 us; speedup vs baseline: 1.1172x; 1.1044x over previous
//
#include <hip/hip_runtime.h>
#include <hip/hip_bf16.h>

// Shapes (fixed): B=4, T=64, L=128, D=768, H=12, d=64
#define NB 4
#define NT 64
#define NL 128
#define ND 768
#define NH 12
#define HD 64

typedef __attribute__((ext_vector_type(8))) short short8;
typedef __attribute__((ext_vector_type(4))) float f32x4;
typedef __attribute__((ext_vector_type(4))) unsigned int u32x4;

typedef __attribute__((address_space(3))) unsigned int lds_u32;
typedef __attribute__((address_space(1))) const unsigned int glob_u32;

static __device__ __forceinline__ unsigned short f2b(float x) {
    __hip_bfloat16 h = __float2bfloat16(x);   // RNE
    return *reinterpret_cast<unsigned short*>(&h);
}
static __device__ __forceinline__ float b2f(unsigned short u) {
    unsigned int v = ((unsigned int)u) << 16;
    union { unsigned int i; float f; } c; c.i = v; return c.f;
}
// async global->LDS, 16B/lane; LDS dest = base + lane*16 (wave-uniform base)
static __device__ __forceinline__ void gl2lds16(const void* g, void* l) {
    __builtin_amdgcn_global_load_lds((glob_u32*)g, (lds_u32*)l, 16, 0, 0);
}
// branchless RNE fp32->bf16 for two elems, packed into one u32 (no NaN in inputs)
static __device__ __forceinline__ unsigned rne2(unsigned lo, unsigned hi) {
    lo += 0x7FFFu + ((lo >> 16) & 1u);
    hi += 0x7FFFu + ((hi >> 16) & 1u);
    return __builtin_amdgcn_perm(hi, lo, 0x07060302u);  // [hi31:16 | lo31:16]
}

// ---------------------------------------------------------------------------
// Kernel 1 (prep_all): union of three roles, one launch:
//  blocks [0,96):      kvm — K/V projection (bf16 MFMA, operands self-converted
//                      from fp32 in-regs) + speaker-bucket scan -> Mt
//  blocks [96,3168):   dense te fp32->bf16 convert (16B/lane @16B stride, ILP-8)
//  blocks [3168,3240): Wq fp32->bf16 convert
// kvm dispatches first -> hides under the BW-bound te stream.
// ---------------------------------------------------------------------------
__global__ __launch_bounds__(256) void prep_all(
    const float* __restrict__ te, const float* __restrict__ Wq,
    const float* __restrict__ edu, const float* __restrict__ Wk,
    const float* __restrict__ Wv, const int* __restrict__ spk,
    unsigned short* __restrict__ te_b, unsigned short* __restrict__ wq_b,
    unsigned short* __restrict__ Mt)
{
    __shared__ __align__(16) unsigned char sm[113920];
    const int tid = threadIdx.x;
    const unsigned bid = blockIdx.x;

    if (bid >= 96u) {
        if (bid < 3168u) {
            // ---- te convert: 6291456 4-float chunks = 3072 * 2048 ----
            const unsigned base = (bid - 96u) * 2048u + tid;
            u32x4 a[8];
            #pragma unroll
            for (int i = 0; i < 8; i++)
                a[i] = __builtin_nontemporal_load((const u32x4*)te + base + i * 256u);
            #pragma unroll
            for (int i = 0; i < 8; i++) {
                uint2 o;
                o.x = rne2(a[i].x, a[i].y);
                o.y = rne2(a[i].z, a[i].w);
                *(uint2*)(te_b + (size_t)(base + i * 256u) * 4u) = o;
            }
        } else {
            // ---- Wq convert: 147456 chunks = 72 * 2048 ----
            const unsigned base = (bid - 3168u) * 2048u + tid;
            u32x4 a[8];
            #pragma unroll
            for (int i = 0; i < 8; i++)
                a[i] = *((const u32x4*)Wq + base + i * 256u);
            #pragma unroll
            for (int i = 0; i < 8; i++) {
                uint2 o;
                o.x = rne2(a[i].x, a[i].y);
                o.y = rne2(a[i].z, a[i].w);
                *(uint2*)(wq_b + (size_t)(base + i * 256u) * 4u) = o;
            }
        }
        return;
    }

    // ---- kvm path: bid < 96 -> (h, b, eh) ----
    const int h  = bid % 12;
    const int b  = (bid / 12) & 3;
    const int eh = bid / 48;

    float (*bucket)[32][65]  = (float (*)[32][65])(sm);            // 66560 B
    float (*k_s)[68]         = (float (*)[68])(sm + 66560);        // 17408 B
    float (*v_s)[36]         = (float (*)[36])(sm + 83968);        //  9216 B
    unsigned short* edu_s    = (unsigned short*)(sm + 93184);      //  8192 B
    unsigned short* wk_s     = edu_s + 4096;                       //  8192 B
    unsigned short* wv_s     = edu_s + 8192;                       //  4096 B
    int* spk_s               = (int*)(sm + 113664);                //   256 B

    const int lane = tid & 63, wvx = tid >> 6;
    const int lr = lane & 15, lg = lane >> 4;

    { float* p = &bucket[0][0][0];
      for (int i = tid; i < 8 * 32 * 65; i += 256) p[i] = 0.f; }
    if (tid < 64) spk_s[tid] = spk[b * NT + tid];

    const float* eduf = edu + (size_t)(b * 64) * ND;
    const float* wkf  = Wk  + (size_t)(h * 64) * ND;
    const float* wvf  = Wv  + (size_t)(h * 64 + eh * 32) * ND;

    f32x4 acc_k[4], acc_v[2];
    #pragma unroll
    for (int i = 0; i < 4; i++) acc_k[i] = (f32x4){0.f, 0.f, 0.f, 0.f};
    #pragma unroll
    for (int i = 0; i < 2; i++) acc_v[i] = (f32x4){0.f, 0.f, 0.f, 0.f};

    for (int k0 = 0; k0 < ND; k0 += 64) {
        __syncthreads();
        // self-convert staging: load fp32 -> rne2 -> swizzled bf16 ds_write
        #pragma unroll
        for (int i = 0; i < 2; i++) {           // edu: 2 chunks/thread
            const int g = tid * 2 + i, row = g >> 3, ch = g & 7;
            const u32x4* p = (const u32x4*)(eduf + (size_t)row * ND + k0 + ch * 8);
            u32x4 x = p[0], y = p[1];
            u32x4 o = { rne2(x.x, x.y), rne2(x.z, x.w), rne2(y.x, y.y), rne2(y.z, y.w) };
            *(u32x4*)&edu_s[row * 64 + ((ch ^ (row & 7)) * 8)] = o;
        }
        #pragma unroll
        for (int i = 0; i < 2; i++) {           // Wk: 2 chunks/thread
            const int g = tid * 2 + i, row = g >> 3, ch = g & 7;
            const u32x4* p = (const u32x4*)(wkf + (size_t)row * ND + k0 + ch * 8);
            u32x4 x = p[0], y = p[1];
            u32x4 o = { rne2(x.x, x.y), rne2(x.z, x.w), rne2(y.x, y.y), rne2(y.z, y.w) };
            *(u32x4*)&wk_s[row * 64 + ((ch ^ (row & 7)) * 8)] = o;
        }
        {                                        // Wv: 1 chunk/thread (32 rows)
            const int g = tid, row = g >> 3, ch = g & 7;
            const u32x4* p = (const u32x4*)(wvf + (size_t)row * ND + k0 + ch * 8);
            u32x4 x = p[0], y = p[1];
            u32x4 o = { rne2(x.x, x.y), rne2(x.z, x.w), rne2(y.x, y.y), rne2(y.z, y.w) };
            *(u32x4*)&wv_s[row * 64 + ((ch ^ (row & 7)) * 8)] = o;
        }
        __syncthreads();
        #pragma unroll
        for (int k32 = 0; k32 < 2; k32++) {
            const int cx = (((k32 * 4 + lg) ^ (lr & 7)) * 8);
            short8 eb = *(const short8*)&edu_s[(wvx * 16 + lr) * 64 + cx];
            #pragma unroll
            for (int jb = 0; jb < 4; jb++) {
                short8 ak = *(const short8*)&wk_s[(jb * 16 + lr) * 64 + cx];
                acc_k[jb] = __builtin_amdgcn_mfma_f32_16x16x32_bf16(ak, eb, acc_k[jb], 0, 0, 0);
            }
            #pragma unroll
            for (int jb = 0; jb < 2; jb++) {
                short8 av = *(const short8*)&wv_s[(jb * 16 + lr) * 64 + cx];
                acc_v[jb] = __builtin_amdgcn_mfma_f32_16x16x32_bf16(av, eb, acc_v[jb], 0, 0, 0);
            }
        }
    }

    {   // fragments -> k_s[t][d], v_s[t][e]  (lane: col t = wvx*16+lr)
        const int t = wvx * 16 + lr;
        #pragma unroll
        for (int jb = 0; jb < 4; jb++) *(f32x4*)&k_s[t][jb * 16 + lg * 4] = acc_k[jb];
        #pragma unroll
        for (int jb = 0; jb < 2; jb++) *(f32x4*)&v_s[t][jb * 16 + lg * 4] = acc_v[jb];
    }
    __syncthreads();

    // ---- bucket scan: thread owns (e = tid&31, d-slice dg*8..dg*8+7) ----
    const int e = tid & 31, dg = tid >> 5;
    for (int t = 0; t < NT; t++) {
        const int s = spk_s[t];
        const float vv = v_s[t][e];
        unsigned short tmp[8];
        #pragma unroll
        for (int jj = 0; jj < 8; jj++) {
            float m = bucket[s][e][dg * 8 + jj] + k_s[t][dg * 8 + jj] * vv;
            bucket[s][e][dg * 8 + jj] = m;
            tmp[jj] = f2b(m);
        }
        unsigned short* mpp = Mt + (((size_t)(b * NT + t) * NH + h) * HD + eh * 32 + e) * HD + dg * 8;
        *(short8*)mpp = *(short8*)tmp;
    }
}

// ---------------------------------------------------------------------------
// Kernel 2: fused bf16 MFMA  q^T = Wq_hp @ te^T (K=768), a = q @ M, residual.
// (round-13 exact — proven ~58.5 us)
// ---------------------------------------------------------------------------
__global__ __launch_bounds__(256, 2) void fused_qm(
    const unsigned short* __restrict__ te_b,
    const unsigned short* __restrict__ wq_b,
    const unsigned short* __restrict__ Mt,
    float* __restrict__ out)
{
    const int orig = blockIdx.x;
    const int id   = (orig & 7) * 192 + (orig >> 3);   // bijective XCD swizzle
    const int hp   = id % 6;
    const int bt   = id / 6;

    __shared__ __align__(16) unsigned short smem[32768];   // 65536 B
    unsigned short* te0 = smem;              // [128][64] swizzled chunks
    unsigned short* te1 = smem + 8192;
    unsigned short* wq0 = smem + 16384;
    unsigned short* wq1 = smem + 24576;
    unsigned short* q_s = smem;              // phase 2: [128][136]

    const int tid  = threadIdx.x;
    const int lane = tid & 63;
    const int wvx  = tid >> 6;
    const int lr   = lane & 15;
    const int lg   = lane >> 4;
    const int wm   = wvx >> 1;
    const int wn   = wvx & 1;
    const int r8   = lane >> 3;
    const int l8   = lane & 7;
    const int sswz = (l8 ^ r8) * 8;          // pre-swizzled source chunk (ush)

    const unsigned short* teb = te_b + (size_t)bt * NL * ND;
    const unsigned short* wqb = wq_b + (size_t)hp * 128 * ND;

    f32x4 acc[4][4];
    #pragma unroll
    for (int i = 0; i < 4; i++)
        #pragma unroll
        for (int j = 0; j < 4; j++) acc[i][j] = (f32x4){0.f, 0.f, 0.f, 0.f};

    auto STAGE = [&](unsigned short* tebuf, unsigned short* wqbuf, int k0) {
        #pragma unroll
        for (int j = 0; j < 4; j++) {
            const int rbase = wvx * 32 + j * 8;     // wave-uniform dest base
            gl2lds16(teb + (size_t)(rbase + r8) * ND + k0 + sswz, tebuf + rbase * 64);
            gl2lds16(wqb + (size_t)(rbase + r8) * ND + k0 + sswz, wqbuf + rbase * 64);
        }
    };
    auto COMPUTE = [&](const unsigned short* tes, const unsigned short* wqs) {
        #pragma unroll
        for (int k32 = 0; k32 < 2; k32++) {
            const int cx = (((k32 * 4 + lg) ^ (lr & 7)) * 8);
            short8 af[4], bfv[4];
            #pragma unroll
            for (int tm = 0; tm < 4; tm++)
                af[tm] = *(const short8*)&wqs[(wm * 64 + tm * 16 + lr) * 64 + cx];
            #pragma unroll
            for (int tn = 0; tn < 4; tn++)
                bfv[tn] = *(const short8*)&tes[(wn * 64 + tn * 16 + lr) * 64 + cx];
            #pragma unroll
            for (int tm = 0; tm < 4; tm++)
                #pragma unroll
                for (int tn = 0; tn < 4; tn++)
                    acc[tm][tn] = __builtin_amdgcn_mfma_f32_16x16x32_bf16(
                        af[tm], bfv[tn], acc[tm][tn], 0, 0, 0);
        }
    };

    // ---- prologue: tile 0 into buf0, full drain once ----
    STAGE(te0, wq0, 0);
    asm volatile("s_waitcnt vmcnt(0)" ::: "memory");
    __builtin_amdgcn_sched_barrier(0);
    __builtin_amdgcn_s_barrier();

    // ---- K-loop: 12 tiles, 2 per iteration, counted vmcnt (never 0 mid-loop)
    #pragma unroll
    for (int kt = 0; kt < 12; kt += 2) {
        STAGE(te1, wq1, (kt + 1) * 64);
        asm volatile("s_waitcnt vmcnt(8)" ::: "memory");   // tile kt complete
        __builtin_amdgcn_sched_barrier(0);
        __builtin_amdgcn_s_barrier();
        COMPUTE(te0, wq0);
        asm volatile("s_waitcnt lgkmcnt(0)" ::: "memory"); // reads retired
        __builtin_amdgcn_s_barrier();                      // buf0 free for reuse
        if (kt + 2 < 12) {
            STAGE(te0, wq0, (kt + 2) * 64);
            asm volatile("s_waitcnt vmcnt(8)" ::: "memory");
        } else {
            asm volatile("s_waitcnt vmcnt(0)" ::: "memory");
        }
        __builtin_amdgcn_sched_barrier(0);
        __builtin_amdgcn_s_barrier();
        COMPUTE(te1, wq1);
        asm volatile("s_waitcnt lgkmcnt(0)" ::: "memory");
        __builtin_amdgcn_s_barrier();                      // buf1 free for reuse
    }

    // ---- q^T C-frags -> row-major bf16 q_s[l][d] (8B packed writes) ----
    #pragma unroll
    for (int tm = 0; tm < 4; tm++) {
        const int d0 = wm * 64 + tm * 16 + lg * 4;
        #pragma unroll
        for (int tn = 0; tn < 4; tn++) {
            const int ltok = wn * 64 + tn * 16 + lr;
            f32x4 a = acc[tm][tn];
            uint2 w2;
            w2.x = (unsigned)f2b(a.x) | ((unsigned)f2b(a.y) << 16);
            w2.y = (unsigned)f2b(a.z) | ((unsigned)f2b(a.w) << 16);
            *(uint2*)&q_s[ltok * 136 + d0] = w2;
        }
    }

    // ---- GEMM2 B-frags straight from global Mt (L2-hot); issue pre-barrier --
    const int h2 = wvx & 1;
    const int lh = wvx >> 1;
    const unsigned short* mp = Mt + ((size_t)(bt * NH) + hp * 2 + h2) * (HD * HD);
    short8 bfr[8];
    #pragma unroll
    for (int tn = 0; tn < 4; tn++)
        #pragma unroll
        for (int k32 = 0; k32 < 2; k32++)
            bfr[tn * 2 + k32] =
                *(const short8*)&mp[(tn * 16 + lr) * 64 + k32 * 32 + lg * 8];
    __syncthreads();            // q_s visible

    // ---- GEMM2: per-wave one (token-half, head), 64x64, K=64 ----
    f32x4 acc2[4][4];
    #pragma unroll
    for (int i = 0; i < 4; i++)
        #pragma unroll
        for (int j = 0; j < 4; j++) acc2[i][j] = (f32x4){0.f, 0.f, 0.f, 0.f};

    #pragma unroll
    for (int k32 = 0; k32 < 2; k32++) {
        const int ko = k32 * 32 + lg * 8;
        short8 af[4];
        #pragma unroll
        for (int tm = 0; tm < 4; tm++)
            af[tm] = *(const short8*)&q_s[(lh * 64 + tm * 16 + lr) * 136 + h2 * 64 + ko];
        #pragma unroll
        for (int tm = 0; tm < 4; tm++)
            #pragma unroll
            for (int tn = 0; tn < 4; tn++)
                acc2[tm][tn] = __builtin_amdgcn_mfma_f32_16x16x32_bf16(
                    af[tm], bfr[tn * 2 + k32], acc2[tm][tn], 0, 0, 0);
    }

    // ---- epilogue: out = bf16(te) + a (te_b L2-hot from staging) ----
    float* ob = out + (size_t)bt * NL * ND;
    #pragma unroll
    for (int tm = 0; tm < 4; tm++) {
        const int l0 = lh * 64 + tm * 16 + lg * 4;
        #pragma unroll
        for (int tn = 0; tn < 4; tn++) {
            const int cg = hp * 128 + h2 * 64 + tn * 16 + lr;
            f32x4 a = acc2[tm][tn];
            #pragma unroll
            for (int r = 0; r < 4; r++) {
                size_t gi = (size_t)(l0 + r) * ND + cg;
                ob[gi] = b2f(teb[gi]) + a[r];
            }
        }
    }
}

// ---------------------------------------------------------------------------
extern "C" void kernel_launch(void* const* d_in, const int* in_sizes, int n_in,
                              void* d_out, int out_size, void* d_ws, size_t ws_size,
                              hipStream_t stream)
{
    const int*   spk = (const int*)d_in[1];
    const float* te  = (const float*)d_in[2];
    const float* edu = (const float*)d_in[3];
    const float* Wk  = (const float*)d_in[4];
    const float* Wv  = (const float*)d_in[5];
    const float* Wq  = (const float*)d_in[6];
    float* out = (float*)d_out;

    // ws layout (ush units), ~76.7 MB total:
    unsigned short* bf    = (unsigned short*)d_ws;
    unsigned short* te_bb = bf;                          // 25165824
    unsigned short* wq_bb = bf + 25165824u;              //   589824
    unsigned short* Mtbuf = bf + 25755648u;              // 12582912

    prep_all<<<3240, 256, 0, stream>>>(te, Wq, edu, Wk, Wv, spk,
                                       te_bb, wq_bb, Mtbuf);
    fused_qm<<<6 * NT * NB, 256, 0, stream>>>(te_bb, wq_bb, Mtbuf, out);
}